// Round 1
// 1662.003 us; speedup vs baseline: 1.0099x; 1.0099x over previous
//
#include <hip/hip_runtime.h>

// Scaled dot product attention, [B=4,H=16,S=2048,D=64] fp32, returns (output, attn).
// d_out layout: output [4*16*2048*64] floats, then attn [4*16*2048*2048] floats.
//
// V2 strategy: barrier-free main kernel.
//   Pre-kernels: K -> bf16 Kb [head][S][D]; V -> bf16 V^T VTb [head][D][S] (workspace).
//   Main kernel: per wave (16 Q-rows), fragments for QK^T and PV are loaded DIRECTLY
//   from global bf16 (perfectly coalesced, L2-resident), so there is no K/V LDS
//   staging and no __syncthreads at all. Only the per-wave P C/D->A layout
//   round-trip LDS remains (same-wave, no barrier). attn stores are nontemporal so
//   the 1.07 GB write stream does not evict K/VT from L2.

#define S 2048
#define D 64
#define BH 64
#define TEMP_INV 0.125f

using short8  = __attribute__((ext_vector_type(8))) short;
using floatx4 = __attribute__((ext_vector_type(4))) float;

static __device__ __forceinline__ short bf(float f) {
  union { float f; unsigned u; } c; c.f = f;
  unsigned r = c.u + 0x7fffu + ((c.u >> 16) & 1u);  // RNE
  return (short)(r >> 16);
}

// ---------------- pre-pass 1: elementwise fp32 -> bf16 (K) ----------------
__global__ __launch_bounds__(256)
void convert_bf16(const float* __restrict__ src, short* __restrict__ dst, int n4) {
  int i = blockIdx.x * 256 + threadIdx.x;
  if (i >= n4) return;
  float4 f = ((const float4*)src)[i];
  short4 o; o.x = bf(f.x); o.y = bf(f.y); o.z = bf(f.z); o.w = bf(f.w);
  ((short4*)dst)[i] = o;
}

// ---------------- pre-pass 2: V [head][s][d] fp32 -> VT [head][d][s] bf16 ----------------
__global__ __launch_bounds__(256)
void transpose_v_bf16(const float* __restrict__ v, short* __restrict__ vt) {
  __shared__ short T[64][72];
  const int head = blockIdx.x >> 5;
  const int s0   = (blockIdx.x & 31) * 64;
  const float4* src = (const float4*)(v + ((size_t)head * S + s0) * D);
  for (int i = threadIdx.x; i < 1024; i += 256) {
    int srow = i >> 4, d4 = (i & 15) * 4;
    float4 f = src[i];
    T[d4 + 0][srow] = bf(f.x);
    T[d4 + 1][srow] = bf(f.y);
    T[d4 + 2][srow] = bf(f.z);
    T[d4 + 3][srow] = bf(f.w);
  }
  __syncthreads();
  short* dst = vt + (size_t)head * D * S + s0;
  for (int i = threadIdx.x; i < 1024; i += 256) {
    int d = i >> 4, c4 = (i & 15) * 4;
    short4 o; o.x = T[d][c4]; o.y = T[d][c4 + 1]; o.z = T[d][c4 + 2]; o.w = T[d][c4 + 3];
    *(short4*)&dst[(size_t)d * S + c4] = o;
  }
}

// ---------------- main kernel: barrier-free ----------------
constexpr int PS = 36;  // P tile row stride, fp32 (16 rows x [32 keys + 4 pad])

__global__ __launch_bounds__(256)
void sdpa_fast(const float* __restrict__ q, const short* __restrict__ kb,
               const short* __restrict__ vtb, float* __restrict__ out) {
  __shared__ float Pl[4][16 * PS];  // per-wave, no barriers needed

  // XCD swizzle: all 32 blocks of a head share blockIdx%8 -> same XCD L2.
  const int g    = blockIdx.x;
  const int xcd  = g & 7;
  const int s_   = g >> 3;            // 0..255
  const int head = xcd + 8 * (s_ >> 5);
  const int qt   = s_ & 31;           // q tile within head, 64 rows each

  const int tid  = threadIdx.x;
  const int wave = tid >> 6;
  const int lane = tid & 63;
  const int quad = lane >> 4;
  const int l16  = lane & 15;

  const size_t headOff = (size_t)head * S * D;
  const int    qrow0   = qt * 64 + wave * 16;   // this wave's first q row

  // Q fragments (registers, whole kernel). A[m=lane&15][kd=quad*8+j].
  const float* qr = q + headOff + (size_t)(qrow0 + l16) * D;
  short8 qa, qb;
#pragma unroll
  for (int j = 0; j < 8; ++j) {
    qa[j] = bf(qr[quad * 8 + j] * TEMP_INV);
    qb[j] = bf(qr[32 + quad * 8 + j] * TEMP_INV);
  }

  const short* kh = kb  + headOff;   // bf16 K, [S][D]
  const short* vh = vtb + headOff;   // bf16 V^T, [D][S]

  // -------- pass 1: row sums of exp(scores), K-frags direct from global --------
  float l[4] = {0.f, 0.f, 0.f, 0.f};
  for (int jt = 0; jt < 32; ++jt) {    // 64 keys per iteration
#pragma unroll
    for (int h = 0; h < 4; ++h) {
      // B[kd=quad*8+j][n=key=l16] = K[key][kd]; wave reads one contiguous 2KB block
      const short* kr = kh + (size_t)(jt * 64 + h * 16 + l16) * D + quad * 8;
      short8 b0 = *(const short8*)kr;
      short8 b1 = *(const short8*)(kr + 32);
      floatx4 acc = {0.f, 0.f, 0.f, 0.f};
      acc = __builtin_amdgcn_mfma_f32_16x16x32_bf16(qa, b0, acc, 0, 0, 0);
      acc = __builtin_amdgcn_mfma_f32_16x16x32_bf16(qb, b1, acc, 0, 0, 0);
#pragma unroll
      for (int r = 0; r < 4; ++r) l[r] += __expf(acc[r]);
    }
  }
  // reduce across the 16 lanes of each quad (they share rows, cover all keys)
#pragma unroll
  for (int off = 1; off < 16; off <<= 1) {
#pragma unroll
    for (int r = 0; r < 4; ++r) l[r] += __shfl_xor(l[r], off);
  }
  float rcp[4];
#pragma unroll
  for (int r = 0; r < 4; ++r) rcp[r] = 1.0f / l[r];

  // -------- pass 2: attn write + PV, all fragments direct from global --------
  floatx4 accO[4];
#pragma unroll
  for (int d0 = 0; d0 < 4; ++d0) accO[d0] = floatx4{0.f, 0.f, 0.f, 0.f};

  float* attn = out + (size_t)BH * S * D;
  float* arow = attn + (size_t)head * S * S + (size_t)qrow0 * S;

  for (int jt = 0; jt < 64; ++jt) {    // 32 keys per iteration
    floatx4 sc[2];
#pragma unroll
    for (int h = 0; h < 2; ++h) {
      const short* kr = kh + (size_t)(jt * 32 + h * 16 + l16) * D + quad * 8;
      short8 b0 = *(const short8*)kr;
      short8 b1 = *(const short8*)(kr + 32);
      floatx4 acc = {0.f, 0.f, 0.f, 0.f};
      acc = __builtin_amdgcn_mfma_f32_16x16x32_bf16(qa, b0, acc, 0, 0, 0);
      acc = __builtin_amdgcn_mfma_f32_16x16x32_bf16(qb, b1, acc, 0, 0, 0);
      sc[h] = acc;
    }

    // normalized p; nontemporal attn store + per-wave P-LDS (no barrier)
#pragma unroll
    for (int h = 0; h < 2; ++h) {
#pragma unroll
      for (int r = 0; r < 4; ++r) {
        float p = __expf(sc[h][r]) * rcp[r];
        __builtin_nontemporal_store(
            p, &arow[(size_t)(quad * 4 + r) * S + jt * 32 + h * 16 + l16]);
        Pl[wave][(quad * 4 + r) * PS + h * 16 + l16] = p;
      }
    }

    // read P back in A-layout: A[m=lane&15][key=quad*8+j], convert to bf16
    float4 pa = *(const float4*)&Pl[wave][l16 * PS + quad * 8];
    float4 pb = *(const float4*)&Pl[wave][l16 * PS + quad * 8 + 4];
    short8 pf;
    pf[0] = bf(pa.x); pf[1] = bf(pa.y); pf[2] = bf(pa.z); pf[3] = bf(pa.w);
    pf[4] = bf(pb.x); pf[5] = bf(pb.y); pf[6] = bf(pb.z); pf[7] = bf(pb.w);

    // PV: B[k=key=quad*8+j][n=d=d0*16+lane&15] = VT[d][key], direct from global
#pragma unroll
    for (int d0 = 0; d0 < 4; ++d0) {
      const short* vr = vh + (size_t)(d0 * 16 + l16) * S + jt * 32 + quad * 8;
      short8 vf = *(const short8*)vr;
      accO[d0] = __builtin_amdgcn_mfma_f32_16x16x32_bf16(pf, vf, accO[d0], 0, 0, 0);
    }
  }

  // epilogue: out[row][d], C/D layout row=quad*4+r, col=d0*16+lane&15
  float* orow = out + headOff;
#pragma unroll
  for (int d0 = 0; d0 < 4; ++d0) {
#pragma unroll
    for (int r = 0; r < 4; ++r) {
      orow[(size_t)(qrow0 + quad * 4 + r) * D + d0 * 16 + l16] = accO[d0][r];
    }
  }
}

// ---------------- fallback (previous verified kernel) if workspace too small ----------------
constexpr int KS  = 72;
constexpr int VTS = 40;

__global__ __launch_bounds__(256)
void sdpa_kernel_ref(const float* __restrict__ q, const float* __restrict__ k,
                     const float* __restrict__ v, float* __restrict__ out) {
  __shared__ __align__(16) short Kt[32 * KS];
  __shared__ __align__(16) short VT[64 * VTS];
  __shared__ __align__(16) float Pl2[4][16 * PS];

  const int g    = blockIdx.x;
  const int xcd  = g & 7;
  const int s    = g >> 3;
  const int head = xcd + 8 * (s >> 5);
  const int qt   = s & 31;

  const int tid  = threadIdx.x;
  const int wave = tid >> 6;
  const int lane = tid & 63;
  const int quad = lane >> 4;
  const int l16  = lane & 15;

  const size_t headOff = (size_t)head * S * D;
  const int    qrow0   = qt * 64 + wave * 16;

  const float* qr = q + headOff + (size_t)(qrow0 + l16) * D;
  short8 qa, qb;
#pragma unroll
  for (int j = 0; j < 8; ++j) {
    qa[j] = bf(qr[quad * 8 + j] * TEMP_INV);
    qb[j] = bf(qr[32 + quad * 8 + j] * TEMP_INV);
  }

  const float* kg = k + headOff;
  const float* vg = v + headOff;

  float l[4] = {0.f, 0.f, 0.f, 0.f};
  for (int jt = 0; jt < 64; ++jt) {
    __syncthreads();
    {
      const float4* src = (const float4*)(kg + (size_t)jt * 32 * D);
#pragma unroll
      for (int i = tid; i < 512; i += 256) {
        float4 f = src[i];
        int key = i >> 4, d4 = (i & 15) * 4;
        short4 sv; sv.x = bf(f.x); sv.y = bf(f.y); sv.z = bf(f.z); sv.w = bf(f.w);
        *(short4*)&Kt[key * KS + d4] = sv;
      }
    }
    __syncthreads();
#pragma unroll
    for (int h = 0; h < 2; ++h) {
      short8 b0 = *(const short8*)&Kt[(h * 16 + l16) * KS + quad * 8];
      short8 b1 = *(const short8*)&Kt[(h * 16 + l16) * KS + 32 + quad * 8];
      floatx4 acc = {0.f, 0.f, 0.f, 0.f};
      acc = __builtin_amdgcn_mfma_f32_16x16x32_bf16(qa, b0, acc, 0, 0, 0);
      acc = __builtin_amdgcn_mfma_f32_16x16x32_bf16(qb, b1, acc, 0, 0, 0);
#pragma unroll
      for (int r = 0; r < 4; ++r) l[r] += __expf(acc[r]);
    }
  }
#pragma unroll
  for (int off = 1; off < 16; off <<= 1) {
#pragma unroll
    for (int r = 0; r < 4; ++r) l[r] += __shfl_xor(l[r], off);
  }
  float rcp[4];
#pragma unroll
  for (int r = 0; r < 4; ++r) rcp[r] = 1.0f / l[r];

  floatx4 accO[4];
#pragma unroll
  for (int d0 = 0; d0 < 4; ++d0) accO[d0] = floatx4{0.f, 0.f, 0.f, 0.f};

  float* attn = out + (size_t)BH * S * D;
  float* arow = attn + (size_t)head * S * S + (size_t)qrow0 * S;

  for (int jt = 0; jt < 64; ++jt) {
    __syncthreads();
    {
      const float4* src = (const float4*)(kg + (size_t)jt * 32 * D);
#pragma unroll
      for (int i = tid; i < 512; i += 256) {
        float4 f = src[i];
        int key = i >> 4, d4 = (i & 15) * 4;
        short4 sv; sv.x = bf(f.x); sv.y = bf(f.y); sv.z = bf(f.z); sv.w = bf(f.w);
        *(short4*)&Kt[key * KS + d4] = sv;
      }
      const float4* vsrc = (const float4*)(vg + (size_t)jt * 32 * D);
#pragma unroll
      for (int i = tid; i < 512; i += 256) {
        float4 f = vsrc[i];
        int key = i >> 4, d4 = (i & 15) * 4;
        VT[(d4 + 0) * VTS + key] = bf(f.x);
        VT[(d4 + 1) * VTS + key] = bf(f.y);
        VT[(d4 + 2) * VTS + key] = bf(f.z);
        VT[(d4 + 3) * VTS + key] = bf(f.w);
      }
    }
    __syncthreads();

    floatx4 sc[2];
#pragma unroll
    for (int h = 0; h < 2; ++h) {
      short8 b0 = *(const short8*)&Kt[(h * 16 + l16) * KS + quad * 8];
      short8 b1 = *(const short8*)&Kt[(h * 16 + l16) * KS + 32 + quad * 8];
      floatx4 acc = {0.f, 0.f, 0.f, 0.f};
      acc = __builtin_amdgcn_mfma_f32_16x16x32_bf16(qa, b0, acc, 0, 0, 0);
      acc = __builtin_amdgcn_mfma_f32_16x16x32_bf16(qb, b1, acc, 0, 0, 0);
      sc[h] = acc;
    }

#pragma unroll
    for (int h = 0; h < 2; ++h) {
#pragma unroll
      for (int r = 0; r < 4; ++r) {
        float p = __expf(sc[h][r]) * rcp[r];
        arow[(size_t)(quad * 4 + r) * S + jt * 32 + h * 16 + l16] = p;
        Pl2[wave][(quad * 4 + r) * PS + h * 16 + l16] = p;
      }
    }

    float4 pa = *(const float4*)&Pl2[wave][l16 * PS + quad * 8];
    float4 pb = *(const float4*)&Pl2[wave][l16 * PS + quad * 8 + 4];
    short8 pf;
    pf[0] = bf(pa.x); pf[1] = bf(pa.y); pf[2] = bf(pa.z); pf[3] = bf(pa.w);
    pf[4] = bf(pb.x); pf[5] = bf(pb.y); pf[6] = bf(pb.z); pf[7] = bf(pb.w);

#pragma unroll
    for (int d0 = 0; d0 < 4; ++d0) {
      short8 vf = *(const short8*)&VT[(d0 * 16 + l16) * VTS + quad * 8];
      accO[d0] = __builtin_amdgcn_mfma_f32_16x16x32_bf16(pf, vf, accO[d0], 0, 0, 0);
    }
  }

  float* orow = out + headOff;
#pragma unroll
  for (int d0 = 0; d0 < 4; ++d0) {
#pragma unroll
    for (int r = 0; r < 4; ++r) {
      orow[(size_t)(qrow0 + quad * 4 + r) * D + d0 * 16 + l16] = accO[d0][r];
    }
  }
}

extern "C" void kernel_launch(void* const* d_in, const int* in_sizes, int n_in,
                              void* d_out, int out_size, void* d_ws, size_t ws_size,
                              hipStream_t stream) {
  const float* q = (const float*)d_in[0];
  const float* k = (const float*)d_in[1];
  const float* v = (const float*)d_in[2];
  float* out = (float*)d_out;

  constexpr size_t ELEMS   = (size_t)BH * S * D;         // 8,388,608
  constexpr size_t WS_NEED = 2 * ELEMS * sizeof(short);  // 32 MiB

  if (d_ws != nullptr && ws_size >= WS_NEED) {
    short* kb  = (short*)d_ws;
    short* vtb = kb + ELEMS;
    convert_bf16<<<(int)(ELEMS / 4 / 256), 256, 0, stream>>>(k, kb, (int)(ELEMS / 4));
    transpose_v_bf16<<<2048, 256, 0, stream>>>(v, vtb);
    sdpa_fast<<<2048, 256, 0, stream>>>(q, kb, vtb, out);
  } else {
    sdpa_kernel_ref<<<2048, 256, 0, stream>>>(q, k, v, out);
  }
}